// Round 9
// baseline (34.995 us; speedup 1.0000x reference)
//
#include <hip/hip_runtime.h>
#include <math.h>

// LightingProbes R9: R8 (16B shared-exp patches, L2-resident 3MB table,
// LDS-staged coalesced I/O) + 2 points per thread at 256-thread blocks.
// Doubles per-wave MLP (8 gathers in flight) + interleaves two selection
// chains to fill dependency bubbles. Per-point math bit-identical to R8.

#define NPATCH 192000            // 6*16*16*125 patches

typedef float vf4 __attribute__((ext_vector_type(4)));
typedef unsigned int u32x4 __attribute__((ext_vector_type(4)));

__device__ __forceinline__ float fastrcp(float x)  { return __builtin_amdgcn_rcpf(x); }
__device__ __forceinline__ float fastsqrt(float x) { return __builtin_amdgcn_sqrtf(x); }

__device__ __forceinline__ void dimsort(float v,
    float& e0, float& e1, float& e2, int& c0, int& c1, int& c2)
{
    float f = (v + 3.0f) * (1.0f / 1.5f);
    int n = (int)floorf(f + 0.5f);
    n = n < 0 ? 0 : (n > 4 ? 4 : n);
    int s = n - 1;
    s = s < 0 ? 0 : (s > 2 ? 2 : s);

    float p0 = fmaf(1.5f, (float)s, -3.0f);
    float d0 = v - p0;
    float d1 = d0 - 1.5f;
    float d2 = d1 - 1.5f;
    float a0 = d0 * d0, a1 = d1 * d1, a2 = d2 * d2;
    int j0 = s, j1 = s + 1, j2 = s + 2;

    {   bool sw = a1 < a0;
        float ta = sw ? a1 : a0, tb = sw ? a0 : a1;
        int   ua = sw ? j1 : j0, ub = sw ? j0 : j1;
        a0 = ta; a1 = tb; j0 = ua; j1 = ub; }
    {   bool sw = a2 < a1;
        float ta = sw ? a2 : a1, tb = sw ? a1 : a2;
        int   ua = sw ? j2 : j1, ub = sw ? j1 : j2;
        a1 = ta; a2 = tb; j1 = ua; j2 = ub; }
    {   bool sw = a1 < a0;
        float ta = sw ? a1 : a0, tb = sw ? a0 : a1;
        int   ua = sw ? j1 : j0, ub = sw ? j0 : j1;
        a0 = ta; a1 = tb; j0 = ua; j1 = ub; }

    e0 = a0; e1 = a1; e2 = a2;
    c0 = j0; c1 = j1; c2 = j2;
}

#define INSERT(d, L, s0, s1, s2, s3, k0, k1, k2, k3)                          \
    {                                                                         \
        bool lt = (d) < s3; s3 = lt ? (d) : s3; k3 = lt ? (L) : k3;           \
        { bool cb = s3 < s2; float nd = cb ? s3 : s2, xd = cb ? s2 : s3;      \
          int ni = cb ? k3 : k2, xi = cb ? k2 : k3;                           \
          s2 = nd; s3 = xd; k2 = ni; k3 = xi; }                               \
        { bool cb = s2 < s1; float nd = cb ? s2 : s1, xd = cb ? s1 : s2;      \
          int ni = cb ? k2 : k1, xi = cb ? k1 : k2;                           \
          s1 = nd; s2 = xd; k1 = ni; k2 = xi; }                               \
        { bool cb = s1 < s0; float nd = cb ? s1 : s0, xd = cb ? s0 : s1;      \
          int ni = cb ? k1 : k0, xi = cb ? k0 : k1;                           \
          s0 = nd; s1 = xd; k0 = ni; k1 = xi; }                               \
    }

__device__ __forceinline__ void uv_setup(
    float dx, float dy, float dz,
    int& face, int& t00,
    float& w00, float& w01, float& w10, float& w11)
{
    float nrm = sqrtf(fmaf(dx, dx, fmaf(dy, dy, dz * dz)));
    nrm = fmaxf(nrm, 1e-12f);
    float inv = fastrcp(nrm);
    float ux = dx * inv, uy = dy * inv, uz = dz * inv;
    float ax = fabsf(ux), ay = fabsf(uy), az = fabsf(uz);

    bool xd = (ax >= ay) && (ax >= az);
    float den, un, vn;
    if (xd) {
        face = (ux > 0.0f) ? 0 : 1;
        den = ax; un = (ux > 0.0f) ? -uz : uz; vn = -uy;
    } else if (ay >= az) {
        face = (uy > 0.0f) ? 2 : 3;
        den = ay; un = ux; vn = (uy > 0.0f) ? uz : -uz;
    } else {
        face = (uz > 0.0f) ? 4 : 5;
        den = az; un = (uz > 0.0f) ? ux : -ux; vn = -uy;
    }
    float rden = fastrcp(den + 1e-8f);
    float u = un * rden;
    float v = vn * rden;
    u = fminf(1.0f, fmaxf(-1.0f, u));
    v = fminf(1.0f, fmaxf(-1.0f, v));

    float fx = (u + 1.0f) * 0.5f * 15.0f;
    float fy = (v + 1.0f) * 0.5f * 15.0f;
    float x0f = floorf(fx), y0f = floorf(fy);
    float wx = fx - x0f, wy = fy - y0f;
    int px0 = (int)x0f; px0 = px0 < 0 ? 0 : (px0 > 15 ? 15 : px0);
    int py0 = (int)y0f; py0 = py0 < 0 ? 0 : (py0 > 15 ? 15 : py0);

    w00 = (1.0f - wx) * (1.0f - wy);
    w01 = wx * (1.0f - wy);
    w10 = (1.0f - wx) * wy;
    w11 = wx * wy;

    t00 = py0 * 16 + px0;
}

// per-point setup -> 4 patch indices + weights
__device__ __forceinline__ void point_setup(
    float x, float y, float z, float dx, float dy, float dz,
    int& pi0, int& pi1, int& pi2, int& pi3,
    float& w0, float& w1, float& w2, float& w3,
    float& w00, float& w01, float& w10, float& w11)
{
    float ex0, ex1, ex2, ey0, ey1, ey2, ez0, ez1, ez2;
    int jx0, jx1, jx2, jy0, jy1, jy2, jz0, jz1, jz2;
    dimsort(x, ex0, ex1, ex2, jx0, jx1, jx2);
    dimsort(y, ey0, ey1, ey2, jy0, jy1, jy2);
    dimsort(z, ez0, ez1, ez2, jz0, jz1, jz2);

    int X0 = jx0 * 25, X1 = jx1 * 25, X2 = jx2 * 25;
    int Y0 = jy0 * 5,  Y1 = jy1 * 5,  Y2 = jy2 * 5;
    int Z0 = jz0,      Z1 = jz1,      Z2 = jz2;

    float exy00 = ex0 + ey0, exy10 = ex1 + ey0, exy01 = ex0 + ey1;
    float exy11 = ex1 + ey1, exy20 = ex2 + ey0, exy02 = ex0 + ey2;
    int   kxy00 = X0 + Y0,   kxy10 = X1 + Y0,   kxy01 = X0 + Y1;
    int   kxy11 = X1 + Y1,   kxy20 = X2 + Y0,   kxy02 = X0 + Y2;

    float s0 = exy00 + ez0, s1 = 1e30f, s2 = 1e30f, s3 = 1e30f;
    int   k0 = kxy00 + Z0,  k1 = 0,     k2 = 0,     k3 = 0;

    { float d = exy10 + ez0; int L = kxy10 + Z0; INSERT(d, L, s0, s1, s2, s3, k0, k1, k2, k3); }
    { float d = exy01 + ez0; int L = kxy01 + Z0; INSERT(d, L, s0, s1, s2, s3, k0, k1, k2, k3); }
    { float d = exy00 + ez1; int L = kxy00 + Z1; INSERT(d, L, s0, s1, s2, s3, k0, k1, k2, k3); }
    { float d = exy11 + ez0; int L = kxy11 + Z0; INSERT(d, L, s0, s1, s2, s3, k0, k1, k2, k3); }
    { float d = exy10 + ez1; int L = kxy10 + Z1; INSERT(d, L, s0, s1, s2, s3, k0, k1, k2, k3); }
    { float d = exy01 + ez1; int L = kxy01 + Z1; INSERT(d, L, s0, s1, s2, s3, k0, k1, k2, k3); }
    { float d = exy20 + ez0; int L = kxy20 + Z0; INSERT(d, L, s0, s1, s2, s3, k0, k1, k2, k3); }
    { float d = exy02 + ez0; int L = kxy02 + Z0; INSERT(d, L, s0, s1, s2, s3, k0, k1, k2, k3); }
    { float d = exy00 + ez2; int L = kxy00 + Z2; INSERT(d, L, s0, s1, s2, s3, k0, k1, k2, k3); }

    w0 = fastrcp(fastsqrt(s0) + 1e-4f);
    w1 = fastrcp(fastsqrt(s1) + 1e-4f);
    w2 = fastrcp(fastsqrt(s2) + 1e-4f);
    w3 = fastrcp(fastsqrt(s3) + 1e-4f);
    float wi = fastrcp(w0 + w1 + w2 + w3);
    w0 *= wi; w1 *= wi; w2 *= wi; w3 *= wi;

    int face, t00;
    uv_setup(dx, dy, dz, face, t00, w00, w01, w10, w11);

    int cell = (face * 256 + t00) * 125;
    pi0 = cell + k0; pi1 = cell + k1; pi2 = cell + k2; pi3 = cell + k3;
}

__device__ __forceinline__ float dec(unsigned w, int sh) {
    return (float)(((int)(w << (22 - sh))) >> 22);
}

__device__ __forceinline__ void decode_accum(
    u32x4 pw, float wn,
    float w00, float w01, float w10, float w11,
    float& r, float& g, float& b)
{
    int E = (int)((pw.x >> 30) | (((pw.y >> 30) & 3u) << 2) | (((pw.z >> 30) & 3u) << 4));
    float s = __uint_as_float((unsigned)(E + 87) << 23);   // 2^(E-40)
    float wns = wn * s;

    float r00 = dec(pw.x, 0),  g00 = dec(pw.x, 10), b00 = dec(pw.x, 20);
    float r01 = dec(pw.y, 0),  g01 = dec(pw.y, 10), b01 = dec(pw.y, 20);
    float r10 = dec(pw.z, 0),  g10 = dec(pw.z, 10), b10 = dec(pw.z, 20);
    float r11 = dec(pw.w, 0),  g11 = dec(pw.w, 10), b11 = dec(pw.w, 20);

    float rr = fmaf(r00, w00, fmaf(r01, w01, fmaf(r10, w10, r11 * w11)));
    float gg = fmaf(g00, w00, fmaf(g01, w01, fmaf(g10, w10, g11 * w11)));
    float bv = fmaf(b00, w00, fmaf(b01, w01, fmaf(b10, w10, b11 * w11)));
    r = fmaf(wns, rr, r);
    g = fmaf(wns, gg, g);
    b = fmaf(wns, bv, b);
}

// ---- build 16B shared-exp patches (identical to R8) ----
__global__ __launch_bounds__(256) void build_patches_se(
    const float* __restrict__ cube, u32x4* __restrict__ patches)
{
    int t = blockIdx.x * blockDim.x + threadIdx.x;
    if (t >= NPATCH) return;
    int p   = t % 125;
    int q   = t / 125;
    int px0 = q % 16; q /= 16;
    int py0 = q % 16;
    int face = q / 16;
    int px1 = px0 + 1 > 15 ? 15 : px0 + 1;
    int py1 = py0 + 1 > 15 ? 15 : py0 + 1;

    const float* f = cube + (p * 6 + face) * 768;
    int o00 = (py0 * 16 + px0) * 3;
    int o01 = (py0 * 16 + px1) * 3;
    int o10 = (py1 * 16 + px0) * 3;
    int o11 = (py1 * 16 + px1) * 3;

    float v[12];
    v[0] = f[o00]; v[1]  = f[o00 + 1]; v[2]  = f[o00 + 2];
    v[3] = f[o01]; v[4]  = f[o01 + 1]; v[5]  = f[o01 + 2];
    v[6] = f[o10]; v[7]  = f[o10 + 1]; v[8]  = f[o10 + 2];
    v[9] = f[o11]; v[10] = f[o11 + 1]; v[11] = f[o11 + 2];

    float mx = 0.0f;
#pragma unroll
    for (int j = 0; j < 12; j++) mx = fmaxf(mx, fabsf(v[j]));

    int E;
    if (mx == 0.0f) {
        E = 0;
    } else {
        unsigned mb = __float_as_uint(mx);
        int eb = (int)((mb >> 23) & 0xFF) - 127;
        E = eb + 32;
        E = E < 0 ? 0 : (E > 63 ? 63 : E);
    }
    float mscale = __uint_as_float((unsigned)(167 - E) << 23);   // 2^(40-E)

    unsigned m[12];
#pragma unroll
    for (int j = 0; j < 12; j++) {
        float s = rintf(v[j] * mscale);
        s = fminf(511.0f, fmaxf(-511.0f, s));
        m[j] = (unsigned)((int)s) & 0x3FF;
    }

    unsigned w0 = m[0] | (m[1] << 10) | (m[2] << 20) | (((unsigned)E & 3) << 30);
    unsigned w1 = m[3] | (m[4] << 10) | (m[5] << 20) | ((((unsigned)E >> 2) & 3) << 30);
    unsigned w2 = m[6] | (m[7] << 10) | (m[8] << 20) | ((((unsigned)E >> 4) & 3) << 30);
    unsigned w3 = m[9] | (m[10] << 10) | (m[11] << 20);

    u32x4 o = {w0, w1, w2, w3};
    patches[t] = o;
}

// ---- main: 512 points per 256-thread block, 2 pts/thread ----
__global__ __launch_bounds__(256) void lp_se2(
    const float* __restrict__ xyz,
    const float* __restrict__ vdirs,
    const u32x4* __restrict__ patches,
    float* __restrict__ out,
    int N)
{
    __shared__ float sh[3072];          // [0..1535] xyz, [1536..3071] dirs

    int tid = threadIdx.x;
    int b0  = blockIdx.x * 512;
    int nPts = N - b0; nPts = nPts > 512 ? 512 : nPts;
    int nflt = nPts * 3;
    int base4 = (b0 * 3) >> 2;          // b0*3 = 1536*blk, divisible by 4

    const vf4* x4 = (const vf4*)xyz;
    const vf4* d4 = (const vf4*)vdirs;
#pragma unroll
    for (int rr = 0; rr < 2; rr++) {
        int idx = tid + rr * 256;
        if (4 * idx + 4 <= nflt) {
            vf4 vx = __builtin_nontemporal_load(&x4[base4 + idx]);
            ((vf4*)sh)[idx] = vx;
            vf4 vd = __builtin_nontemporal_load(&d4[base4 + idx]);
            ((vf4*)(sh + 1536))[idx] = vd;
        }
    }
    {   // scalar remainder (nflt % 4 floats), tail block only
        int rem = nflt & 3;
        int basef = nflt & ~3;
        if (tid < rem) {
            sh[basef + tid]        = xyz[b0 * 3 + basef + tid];
            sh[1536 + basef + tid] = vdirs[b0 * 3 + basef + tid];
        }
    }
    __syncthreads();

    int la = tid, lb = tid + 256;
    bool hasA = la < nPts, hasB = lb < nPts;

    float xA  = sh[3 * la + 0],        yA  = sh[3 * la + 1],        zA  = sh[3 * la + 2];
    float dxA = sh[1536 + 3 * la + 0], dyA = sh[1536 + 3 * la + 1], dzA = sh[1536 + 3 * la + 2];
    float xB  = sh[3 * lb + 0],        yB  = sh[3 * lb + 1],        zB  = sh[3 * lb + 2];
    float dxB = sh[1536 + 3 * lb + 0], dyB = sh[1536 + 3 * lb + 1], dzB = sh[1536 + 3 * lb + 2];
    // (garbage beyond nflt is harmless: all derived indices are clamped in-range)

    int piA0, piA1, piA2, piA3, piB0, piB1, piB2, piB3;
    float wA0, wA1, wA2, wA3, wB0, wB1, wB2, wB3;
    float wA00, wA01, wA10, wA11, wB00, wB01, wB10, wB11;
    point_setup(xA, yA, zA, dxA, dyA, dzA, piA0, piA1, piA2, piA3,
                wA0, wA1, wA2, wA3, wA00, wA01, wA10, wA11);
    point_setup(xB, yB, zB, dxB, dyB, dzB, piB0, piB1, piB2, piB3,
                wB0, wB1, wB2, wB3, wB00, wB01, wB10, wB11);

    // 8 independent gathers in flight
    u32x4 pA0 = patches[piA0];
    u32x4 pA1 = patches[piA1];
    u32x4 pA2 = patches[piA2];
    u32x4 pA3 = patches[piA3];
    u32x4 pB0 = patches[piB0];
    u32x4 pB1 = patches[piB1];
    u32x4 pB2 = patches[piB2];
    u32x4 pB3 = patches[piB3];

    float rA = 0.0f, gA = 0.0f, bA = 0.0f;
    float rB = 0.0f, gB = 0.0f, bB = 0.0f;
    decode_accum(pA0, wA0, wA00, wA01, wA10, wA11, rA, gA, bA);
    decode_accum(pA1, wA1, wA00, wA01, wA10, wA11, rA, gA, bA);
    decode_accum(pA2, wA2, wA00, wA01, wA10, wA11, rA, gA, bA);
    decode_accum(pA3, wA3, wA00, wA01, wA10, wA11, rA, gA, bA);
    decode_accum(pB0, wB0, wB00, wB01, wB10, wB11, rB, gB, bB);
    decode_accum(pB1, wB1, wB00, wB01, wB10, wB11, rB, gB, bB);
    decode_accum(pB2, wB2, wB00, wB01, wB10, wB11, rB, gB, bB);
    decode_accum(pB3, wB3, wB00, wB01, wB10, wB11, rB, gB, bB);

    __syncthreads();
    if (hasA) { sh[3 * la + 0] = rA; sh[3 * la + 1] = gA; sh[3 * la + 2] = bA; }
    if (hasB) { sh[3 * lb + 0] = rB; sh[3 * lb + 1] = gB; sh[3 * lb + 2] = bB; }
    __syncthreads();

#pragma unroll
    for (int rr = 0; rr < 2; rr++) {
        int idx = tid + rr * 256;
        if (4 * idx + 4 <= nflt) {
            vf4* o4 = (vf4*)out;
            __builtin_nontemporal_store(((vf4*)sh)[idx], &o4[base4 + idx]);
        }
    }
    {
        int rem = nflt & 3;
        int basef = nflt & ~3;
        if (tid < rem) out[b0 * 3 + basef + tid] = sh[basef + tid];
    }
}

extern "C" void kernel_launch(void* const* d_in, const int* in_sizes, int n_in,
                              void* d_out, int out_size, void* d_ws, size_t ws_size,
                              hipStream_t stream) {
    const float* xyz  = (const float*)d_in[0];
    const float* vd   = (const float*)d_in[1];
    const float* cube = (const float*)d_in[2];
    float* outp = (float*)d_out;
    int N = in_sizes[0] / 3;
    int blocks = (N + 511) / 512;

    u32x4* patches = (u32x4*)d_ws;    // 3.07 MB
    hipLaunchKernelGGL(build_patches_se, dim3((NPATCH + 255) / 256), dim3(256), 0, stream,
                       cube, patches);
    hipLaunchKernelGGL(lp_se2, dim3(blocks), dim3(256), 0, stream,
                       xyz, vd, patches, outp, N);
}